// Round 4
// baseline (241.129 us; speedup 1.0000x reference)
//
#include <hip/hip_runtime.h>

// LaBramChannelPatcher: [B=16, W=32, T=1000, C=64] fp32 ->
//   patches [B, W, C*nt=320, P=200]  (== per-(b,w) transpose [T,C] -> [C,T])
//   channel_indices [320] = repeat(arange(64), 5)
//   time_indices    [320] = tile(arange(5), 64)
//
// Round-4 = round-3 with the index-epilogue tail bug fixed (256 threads
// couldn't cover 320 entries with a single `tid < 320` guard; entries
// 256..319 were unwritten -> Output 1 absmax 63).
//
// Round-3 design (unchanged, theory still under test):
//  - Block = (bw, channel-quad): LDS 16 KB -> 8 blocks/CU, 32 waves/CU.
//    8 staggered blocks per CU keep reads AND writes in flight concurrently
//    (fix for the 2-blocks/CU phase convoy that pinned us at 50% of copy BW).
//  - LDS stored ALREADY TRANSPOSED: lds[c][1000 t]. Phase-1 scatter via 4
//    lane-sequential ds_write_b32 (conflict-free). Phase-2 is a pure
//    sequential copy: dst4[i] = lds4[i] (ds_read_b128 + float4 stores).
//  - Output region per block: contiguous 16000 B = 125 exact cache lines,
//    block-exclusive.
//  - XCD-chunked swizzle: all 16 cq-blocks of one bw co-resident on the SAME
//    XCD -> 4-way read line sharing resolves in that XCD's L2.

#define TDIM 1000
#define PATCH_ELEMS 32768000    // 16*32*320*200

__global__ __launch_bounds__(256, 8) void labram_patcher_kernel(
    const float* __restrict__ in, float* __restrict__ out)
{
    __shared__ float lds[4 * TDIM];   // [c][t], 16 KB, no padding needed

    const int tid  = threadIdx.x;
    const int phys = blockIdx.x;
    // bijective XCD-chunk swizzle (8192 blocks = 8 XCDs * 1024)
    const int virt = (phys & 7) * 1024 + (phys >> 3);
    const int bw = virt >> 4;         // 0..511  (b*32 + w)
    const int cq = virt & 15;         // channel quad 0..15 (4 channels each)

    // ---- Phase 1: load 16 B per t-row (stride 256 B), scatter-transpose
    //      into lds[c][t]. Loads batch-issue (reg-staged), ds_writes are
    //      lane-sequential per component -> conflict-free. ----
    const float4* gsrc = (const float4*)in + (size_t)bw * 16000 + cq;

    float4 v[4];
    #pragma unroll
    for (int k = 0; k < 3; ++k)
        v[k] = gsrc[(size_t)(tid + k * 256) * 16];
    const int t3 = tid + 768;
    if (t3 < TDIM)
        v[3] = gsrc[(size_t)t3 * 16];

    #pragma unroll
    for (int k = 0; k < 4; ++k) {
        const int t = tid + k * 256;
        if (k < 3 || t < TDIM) {
            lds[            t] = v[k].x;
            lds[    TDIM +  t] = v[k].y;
            lds[2 * TDIM +  t] = v[k].z;
            lds[3 * TDIM +  t] = v[k].w;
        }
    }
    __syncthreads();

    // ---- Phase 2: transpose already done in LDS; pure sequential copy.
    //      ds_read_b128 + contiguous float4 stores (block region = 16000 B,
    //      125 exact cache lines, block-exclusive). ----
    const float4* lds4 = (const float4*)lds;   // 1000 float4
    float4* dst = (float4*)out + (size_t)bw * 16000 + (size_t)cq * 1000;

    #pragma unroll
    for (int k = 0; k < 4; ++k) {
        const int i = tid + k * 256;
        if (k < 3 || i < 1000)
            dst[i] = lds4[i];
    }

    // ---- Index outputs (tiny): one block, grid-stride over all 320 ----
    if (phys == 0) {
        for (int i = tid; i < 320; i += 256) {
            out[PATCH_ELEMS + i]       = (float)(i / 5);  // channel_indices
            out[PATCH_ELEMS + 320 + i] = (float)(i % 5);  // time_indices
        }
    }
}

extern "C" void kernel_launch(void* const* d_in, const int* in_sizes, int n_in,
                              void* d_out, int out_size, void* d_ws, size_t ws_size,
                              hipStream_t stream) {
    const float* in = (const float*)d_in[0];
    float* out = (float*)d_out;
    dim3 grid(512 * 16);   // 512 (b,w) slices * 16 channel-quads
    dim3 block(256);
    labram_patcher_kernel<<<grid, block, 0, stream>>>(in, out);
}